// Round 4
// baseline (7236.118 us; speedup 1.0000x reference)
//
#include <hip/hip_runtime.h>

#define BATCH 32
#define HW_ 900
#define NL_ 20
#define DIM_ 512
#define LIN_ 768
#define G_ 8            // batches per group
#define NGRP 4
#define MG (G_ * HW_)   // 7200 rows per group

// ---------------------------------------------------------------------------
// f32 tiled GEMM: C = act( A1*W1^T [+ A2*W2^T] + b1 [+ b2] ) [+ addend]
// W is (N x K) row-major. 64x64 tile, BK=16, 256 threads, 4x4 per thread.
// N must be a multiple of 64 and covered exactly by grid.y (all calls N=512).
// addend/C intentionally NOT __restrict__ (final GEMM aliases them; each
// thread reads its own element before writing it).
// ---------------------------------------------------------------------------
#define BM 64
#define BN 64
#define BK 16
#define LPAD 68

template<int ACT, int PAIRS, int HASADD>
__global__ __launch_bounds__(256)
void sgemm(const float* __restrict__ A1, const float* __restrict__ W1,
           const float* __restrict__ A2, const float* __restrict__ W2,
           const float* __restrict__ b1, const float* __restrict__ b2,
           const float* add, float* C,
           int M, int N, int K1, int lda, int ldw,
           int K2, int lda2, int ldw2, int ldc)
{
  __shared__ float As[BK][LPAD];
  __shared__ float Ws[BK][LPAD];
  const int m0 = blockIdx.x * BM, n0 = blockIdx.y * BN;
  const int tid = threadIdx.x;
  const int srow = tid >> 2, sk = (tid & 3) * 4;   // staging: 64 rows x 16 k
  const int cx = tid & 15, ry = tid >> 4;          // compute: col-group, row-group
  float acc[4][4] = {};

  for (int p = 0; p < PAIRS; ++p) {
    const float* A = p ? A2 : A1;
    const float* W = p ? W2 : W1;
    const int la = p ? lda2 : lda, lw = p ? ldw2 : ldw, K = p ? K2 : K1;
    const int gm = m0 + srow, gn = n0 + srow;
    const float* ap = A + (long)gm * la;
    const float* wp = W + (long)gn * lw;
    for (int kb = 0; kb < K; kb += BK) {
      float4 av = make_float4(0, 0, 0, 0);
      if (gm < M) av = *(const float4*)(ap + kb + sk);
      float4 wv = *(const float4*)(wp + kb + sk);   // gn < N always (N=512)
      __syncthreads();
      As[sk + 0][srow] = av.x; As[sk + 1][srow] = av.y;
      As[sk + 2][srow] = av.z; As[sk + 3][srow] = av.w;
      Ws[sk + 0][srow] = wv.x; Ws[sk + 1][srow] = wv.y;
      Ws[sk + 2][srow] = wv.z; Ws[sk + 3][srow] = wv.w;
      __syncthreads();
      #pragma unroll
      for (int k = 0; k < BK; ++k) {
        float4 a = *(const float4*)&As[k][ry * 4];
        float4 b = *(const float4*)&Ws[k][cx * 4];
        float aa[4] = {a.x, a.y, a.z, a.w};
        float bb[4] = {b.x, b.y, b.z, b.w};
        #pragma unroll
        for (int i = 0; i < 4; ++i)
          #pragma unroll
          for (int j = 0; j < 4; ++j) acc[i][j] += aa[i] * bb[j];
      }
    }
  }

  const int gn = n0 + cx * 4;
  float bs[4] = {0, 0, 0, 0};
  if (b1) { for (int j = 0; j < 4; ++j) bs[j] += b1[gn + j]; }
  if (PAIRS == 2 && b2) { for (int j = 0; j < 4; ++j) bs[j] += b2[gn + j]; }
  #pragma unroll
  for (int i = 0; i < 4; ++i) {
    int gm = m0 + ry * 4 + i;
    if (gm >= M) continue;
    float ov[4];
    #pragma unroll
    for (int j = 0; j < 4; ++j) {
      float xv = acc[i][j] + bs[j];
      if (ACT == 1) xv = fmaxf(xv, 0.f);
      if (ACT == 2) xv = tanhf(xv);
      ov[j] = xv;
    }
    if (HASADD) {
      float4 ad = *(const float4*)(add + (long)gm * ldc + gn);
      ov[0] += ad.x; ov[1] += ad.y; ov[2] += ad.z; ov[3] += ad.w;
    }
    float4 o; o.x = ov[0]; o.y = ov[1]; o.z = ov[2]; o.w = ov[3];
    *(float4*)(C + (long)gm * ldc + gn) = o;
  }
}

// ---------------------------------------------------------------------------
// lt[b,n,d] = sum_c l[b,c,n] * W_lang[d,c] + b_lang[d].  One block per (b,n).
// ---------------------------------------------------------------------------
__global__ __launch_bounds__(256)
void lt_kernel(const float* __restrict__ l, const float* __restrict__ Wl,
               const float* __restrict__ bl, float* __restrict__ Lt)
{
  __shared__ float lc[LIN_];
  const int b = blockIdx.x / NL_, n = blockIdx.x % NL_;
  const int tid = threadIdx.x;
  const float* lb = l + (long)b * LIN_ * NL_;
  for (int c = tid; c < LIN_; c += 256) lc[c] = lb[c * NL_ + n];
  __syncthreads();
  for (int d = tid; d < DIM_; d += 256) {
    const float* w = Wl + (long)d * LIN_;
    float acc = 0.f;
    for (int c = 0; c < LIN_; c += 4) {
      float4 wf = *(const float4*)&w[c];
      acc += lc[c] * wf.x + lc[c + 1] * wf.y + lc[c + 2] * wf.z + lc[c + 3] * wf.w;
    }
    Lt[((long)b * NL_ + n) * DIM_ + d] = acc + bl[d];
  }
}

// ---------------------------------------------------------------------------
// Fused language attention over NL=20 tokens (f32). Q/O are group-local
// (bg = batch within group); Lt/lmask indexed by global batch.
// ---------------------------------------------------------------------------
__global__ __launch_bounds__(256)
void attn_kernel(const float* __restrict__ Q, const float* __restrict__ Lt,
                 const float* __restrict__ lmask, float* __restrict__ O,
                 int bbase)
{
  __shared__ float lt[NL_ * DIM_];   // 40 KB
  __shared__ float smask[NL_];
  const int bg = blockIdx.y, b = bbase + bg;
  const int tid = threadIdx.x;
  const float* Lb = Lt + (long)b * NL_ * DIM_;
  for (int i = tid; i < NL_ * DIM_ / 4; i += 256)
    *(float4*)&lt[i * 4] = *(const float4*)&Lb[i * 4];
  if (tid < NL_) smask[tid] = 10000.f * lmask[b * NL_ + tid] - 10000.f;
  __syncthreads();
  const int wid = tid >> 6, lane = tid & 63;
  for (int rr = 0; rr < 2; ++rr) {
    int h = blockIdx.x * 8 + wid * 2 + rr;
    if (h >= HW_) continue;  // wave-uniform
    long grow = ((long)bg * HW_ + h) * DIM_;
    float4 q0 = *(const float4*)&Q[grow + lane * 8];
    float4 q1 = *(const float4*)&Q[grow + lane * 8 + 4];
    float sim[NL_];
    for (int n = 0; n < NL_; ++n) {
      const float* lv = &lt[n * DIM_ + lane * 8];
      float4 l0 = *(const float4*)lv, l1 = *(const float4*)(lv + 4);
      float d = q0.x * l0.x + q0.y * l0.y + q0.z * l0.z + q0.w * l0.w
              + q1.x * l1.x + q1.y * l1.y + q1.z * l1.z + q1.w * l1.w;
      #pragma unroll
      for (int m = 32; m >= 1; m >>= 1) d += __shfl_xor(d, m, 64);
      sim[n] = d + smask[n];
    }
    float mx = sim[0];
    #pragma unroll
    for (int n = 1; n < NL_; ++n) mx = fmaxf(mx, sim[n]);
    float s = 0.f;
    #pragma unroll
    for (int n = 0; n < NL_; ++n) { sim[n] = expf(sim[n] - mx); s += sim[n]; }
    float inv = 1.f / s;
    float o[8] = {0, 0, 0, 0, 0, 0, 0, 0};
    for (int n = 0; n < NL_; ++n) {
      float pn = sim[n] * inv;
      const float* lv = &lt[n * DIM_ + lane * 8];
      float4 l0 = *(const float4*)lv, l1 = *(const float4*)(lv + 4);
      o[0] += pn * l0.x; o[1] += pn * l0.y; o[2] += pn * l0.z; o[3] += pn * l0.w;
      o[4] += pn * l1.x; o[5] += pn * l1.y; o[6] += pn * l1.z; o[7] += pn * l1.w;
    }
    float4 o0 = make_float4(o[0], o[1], o[2], o[3]);
    float4 o1 = make_float4(o[4], o[5], o[6], o[7]);
    *(float4*)&O[grow + lane * 8] = o0;
    *(float4*)&O[grow + lane * 8 + 4] = o1;
  }
}

// ---------------------------------------------------------------------------
// Fused: S = Apre @ W_a^T + b_a (16 rows x 900, f32 in LDS) -> row softmax
// -> out2 = S @ q3. One block per (16-row tile, batch-in-group). Out2
// overwrites Apre in place (block-private rows). LDS stride 905 (f32):
// 905 % 32 = 9 -> lanes r=0..15 hit 16 distinct banks in pass 2.
// LDS: 16*905*4 = 57,920 B.
// ---------------------------------------------------------------------------
#define SST 905

__global__ __launch_bounds__(256)
void fuse_rel(const float* Apre, const float* __restrict__ Wa,
              const float* __restrict__ ba, const float* __restrict__ Q3,
              float* Out2)
{
  __shared__ float S[16 * SST];
  const int mt = blockIdx.x, bg = blockIdx.y;
  const int r0 = mt * 16;
  const int tid = threadIdx.x;
  const int r = tid & 15, cq = tid >> 4;
  const long abase = (long)bg * HW_ * DIM_;
  const int grow = r0 + r;
  const bool rv = grow < HW_;
  const float* arow = Apre + abase + (long)grow * DIM_;

  // ---- Pass 1: scores ----
  for (int wt = 0; wt < 15; ++wt) {
    int c0 = wt * 64 + cq * 4;
    float acc[4] = {0, 0, 0, 0};
    if (rv) {
      const float* w0 = Wa + (long)(c0 + 0) * DIM_;
      const float* w1 = Wa + (long)(c0 + 1) * DIM_;
      const float* w2 = Wa + (long)(c0 + 2) * DIM_;
      const float* w3 = Wa + (long)(c0 + 3) * DIM_;
      bool cv = (c0 + 3) < HW_;        // c0 multiples of 4; only tail tile partial
      for (int k = 0; k < DIM_; k += 4) {
        float4 a = *(const float4*)&arow[k];
        float4 v0 = *(const float4*)&w0[k];
        float4 v1 = *(const float4*)&w1[k];
        float4 v2, v3;
        if (cv) { v2 = *(const float4*)&w2[k]; v3 = *(const float4*)&w3[k]; }
        else    { v2 = make_float4(0,0,0,0);   v3 = make_float4(0,0,0,0);   }
        acc[0] += a.x * v0.x + a.y * v0.y + a.z * v0.z + a.w * v0.w;
        acc[1] += a.x * v1.x + a.y * v1.y + a.z * v1.z + a.w * v1.w;
        acc[2] += a.x * v2.x + a.y * v2.y + a.z * v2.z + a.w * v2.w;
        acc[3] += a.x * v3.x + a.y * v3.y + a.z * v3.z + a.w * v3.w;
      }
    }
    #pragma unroll
    for (int j = 0; j < 4; ++j) {
      int c = c0 + j;
      if (c < HW_) S[r * SST + c] = rv ? acc[j] + ba[c] : 0.f;
    }
  }
  __syncthreads();

  // ---- Softmax: 4 waves x 4 rows ----
  const int wid = tid >> 6, lane = tid & 63;
  for (int rr = 0; rr < 4; ++rr) {
    int row = wid * 4 + rr;
    float* sp = &S[row * SST];
    float vals[15];
    float mx = -1e30f;
    #pragma unroll
    for (int i = 0; i < 15; ++i) {
      int idx = lane + i * 64;
      vals[i] = (idx < HW_) ? sp[idx] : -1e30f;
      mx = fmaxf(mx, vals[i]);
    }
    #pragma unroll
    for (int m = 32; m >= 1; m >>= 1) mx = fmaxf(mx, __shfl_xor(mx, m, 64));
    float s = 0.f;
    #pragma unroll
    for (int i = 0; i < 15; ++i) {
      int idx = lane + i * 64;
      if (idx < HW_) { vals[i] = expf(vals[i] - mx); s += vals[i]; }
    }
    #pragma unroll
    for (int m = 32; m >= 1; m >>= 1) s += __shfl_xor(s, m, 64);
    float inv = 1.f / s;
    #pragma unroll
    for (int i = 0; i < 15; ++i) {
      int idx = lane + i * 64;
      if (idx < HW_) sp[idx] = vals[i] * inv;
    }
  }
  __syncthreads();

  // ---- Pass 2: out2 = S @ q3 ----
  const int dg = tid >> 4;                 // d-range dg*32 .. +32
  float4 acc2[8] = {};
  const float* q3b = Q3 + abase;
  for (int w = 0; w < HW_; ++w) {
    float s = S[r * SST + w];
    const float* qr = q3b + (long)w * DIM_ + dg * 32;
    #pragma unroll
    for (int j = 0; j < 8; ++j) {
      float4 qv = *(const float4*)&qr[j * 4];
      acc2[j].x += s * qv.x; acc2[j].y += s * qv.y;
      acc2[j].z += s * qv.z; acc2[j].w += s * qv.w;
    }
  }
  if (rv) {
    float* orow = Out2 + abase + (long)grow * DIM_ + dg * 32;
    #pragma unroll
    for (int j = 0; j < 8; ++j) *(float4*)&orow[j * 4] = acc2[j];
  }
}

// ---------------------------------------------------------------------------
__global__ void diag_kernel(float* out, long n, float ws_mb)
{
  long i = (long)blockIdx.x * 256 + threadIdx.x;
  if (i < n) out[i] = 0.f;
  if (i == 0) out[0] = ws_mb;
}

// ---------------------------------------------------------------------------
extern "C" void kernel_launch(void* const* d_in, const int* in_sizes, int n_in,
                              void* d_out, int out_size, void* d_ws, size_t ws_size,
                              hipStream_t stream) {
  const float* x      = (const float*)d_in[0];
  const float* l      = (const float*)d_in[1];
  const float* lmask  = (const float*)d_in[2];
  const float* W_lang = (const float*)d_in[3];
  const float* b_lang = (const float*)d_in[4];
  const float* W_v1   = (const float*)d_in[5];  const float* b_v1   = (const float*)d_in[6];
  const float* W_v2   = (const float*)d_in[7];  const float* b_v2   = (const float*)d_in[8];
  const float* W_v3   = (const float*)d_in[9];  const float* b_v3   = (const float*)d_in[10];
  const float* W_v4   = (const float*)d_in[11]; const float* b_v4   = (const float*)d_in[12];
  const float* W_out1 = (const float*)d_in[13]; const float* b_out1 = (const float*)d_in[14];
  const float* W_v22  = (const float*)d_in[15]; const float* b_v22  = (const float*)d_in[16];
  const float* W_a    = (const float*)d_in[17]; const float* b_a    = (const float*)d_in[18];
  const float* W_o3   = (const float*)d_in[19]; const float* b_o3   = (const float*)d_in[20];
  float* out = (float*)d_out;

  const size_t nG  = (size_t)MG * DIM_;              // 3,686,400 f32 per group buffer
  const size_t nLt = (size_t)BATCH * NL_ * DIM_;     // 327,680 f32
  const size_t need = (3 * nG + nLt) * sizeof(float);  // 45,547,520 B

  if (ws_size < need) {
    long n = (long)out_size;
    diag_kernel<<<dim3((unsigned)((n + 255) / 256)), dim3(256), 0, stream>>>(
        out, n, (float)(ws_size >> 20));
    return;
  }

  float* ws = (float*)d_ws;
  float* O  = ws;            // attention out (group)
  float* Ap = O + nG;        // Apre -> out2 in place (group)
  float* Q3 = Ap + nG;       // q3 (group)
  float* Lt = Q3 + nG;       // (B, 20, 512), all batches

  dim3 blk(256);
  dim3 gg((MG + BM - 1) / BM, DIM_ / BN);   // (113, 8)

  // 1. lt (all batches)
  lt_kernel<<<dim3(BATCH * NL_), blk, 0, stream>>>(l, W_lang, b_lang, Lt);

  for (int g = 0; g < NGRP; ++g) {
    const float* xg = x + (size_t)g * nG;
    float* outg = out + (size_t)g * nG;
    // 2. q1 = relu(x W_v1^T + b) -> d_out rows of this group
    sgemm<1,1,0><<<gg, blk, 0, stream>>>(
        xg, W_v1, nullptr, nullptr, b_v1, nullptr, nullptr, outg,
        MG, DIM_, DIM_, DIM_, DIM_, 0, 0, 0, DIM_);
    // 3. attention -> O
    attn_kernel<<<dim3(113, G_), blk, 0, stream>>>(outg, Lt, lmask, O, g * G_);
    // 4. q2 -> d_out
    sgemm<1,1,0><<<gg, blk, 0, stream>>>(
        xg, W_v2, nullptr, nullptr, b_v2, nullptr, nullptr, outg,
        MG, DIM_, DIM_, DIM_, DIM_, 0, 0, 0, DIM_);
    // 5. Apre = tanh(O W_out1^T + q2 W_v22^T + b+b) -> Ap
    sgemm<2,2,0><<<gg, blk, 0, stream>>>(
        O, W_out1, outg, W_v22, b_out1, b_v22, nullptr, Ap,
        MG, DIM_, DIM_, DIM_, DIM_, DIM_, DIM_, DIM_, DIM_);
    // 6. q3 = relu(x W_v3^T + b) -> Q3
    sgemm<1,1,0><<<gg, blk, 0, stream>>>(
        xg, W_v3, nullptr, nullptr, b_v3, nullptr, nullptr, Q3,
        MG, DIM_, DIM_, DIM_, DIM_, 0, 0, 0, DIM_);
    // 7. fused rel_map softmax + out2 (overwrites Ap)
    fuse_rel<<<dim3(57, G_), blk, 0, stream>>>(Ap, W_a, b_a, Q3, Ap);
    // 8. q4 -> d_out
    sgemm<1,1,0><<<gg, blk, 0, stream>>>(
        xg, W_v4, nullptr, nullptr, b_v4, nullptr, nullptr, outg,
        MG, DIM_, DIM_, DIM_, DIM_, 0, 0, 0, DIM_);
    // 9. out = relu(out2 Wo3[:,:512]^T + O Wo3[:,512:]^T + b_o3) + q4
    //    addend (q4) aliases C: same-element read-before-write, safe.
    sgemm<1,2,1><<<gg, blk, 0, stream>>>(
        Ap, W_o3, O, W_o3 + DIM_, b_o3, nullptr, outg, outg,
        MG, DIM_, DIM_, DIM_, DIM_ * 2, DIM_, DIM_, DIM_ * 2, DIM_);
  }
}

// Round 5
// 3526.627 us; speedup vs baseline: 2.0519x; 2.0519x over previous
//
#include <hip/hip_runtime.h>

#define BATCH 32
#define HW_ 900
#define NL_ 20
#define DIM_ 512
#define LIN_ 768
#define G_ 8            // batches per group (regular GEMM phase)
#define NGRP 4
#define MG (G_ * HW_)   // 7200 rows per group
#define HB 4            // batches per half-group (S / out2 phase)
#define MH (HB * HW_)   // 3600
#define SPAD 912        // S row stride (57*16, zero-padded cols 900..911)

// ---------------------------------------------------------------------------
// f32 TN GEMM: C = act( A1*W1^T [+ A2*W2^T] + b1 [+ b2] ) [+ addend]
// A (M x K) lda, W (N x K) row-major ldw. 128x64 tile, BK=16, 256 threads,
// 8x4 acc per thread. Guards on M rows and N cols (N%4==0 assumed).
// addend/C NOT __restrict__ (final GEMM aliases them; per-thread same-element
// read-before-write).
// ---------------------------------------------------------------------------
#define BM 128
#define BN 64
#define BK 16

template<int ACT, int PAIRS, int HASADD>
__global__ __launch_bounds__(256)
void sgemm_tn(const float* __restrict__ A1, const float* __restrict__ W1,
              const float* __restrict__ A2, const float* __restrict__ W2,
              const float* __restrict__ b1, const float* __restrict__ b2,
              const float* add, float* C,
              int M, int N, int K1, int lda, int ldw,
              int K2, int lda2, int ldw2, int ldc)
{
  __shared__ float As[BK][BM + 4];   // 8448 B
  __shared__ float Ws[BK][BN + 4];   // 4352 B
  const int m0 = blockIdx.x * BM, n0 = blockIdx.y * BN;
  const int tid = threadIdx.x;
  const int arow = tid >> 1, ak = (tid & 1) * 8;   // A staging: 128 rows x 16k
  const int wrow = tid >> 2, wk = (tid & 3) * 4;   // W staging: 64 rows x 16k
  const int cx = tid & 15, ry = tid >> 4;          // compute: col-grp(4), row-grp(8)
  float acc[8][4] = {};

  for (int p = 0; p < PAIRS; ++p) {
    const float* A = p ? A2 : A1;
    const float* W = p ? W2 : W1;
    const int la = p ? lda2 : lda, lw = p ? ldw2 : ldw, K = p ? K2 : K1;
    const int gm = m0 + arow, gn = n0 + wrow;
    const float* ap = A + (long)gm * la;
    const float* wp = W + (long)gn * lw;
    const bool av_ok = gm < M, wv_ok = gn < N;
    for (int kb = 0; kb < K; kb += BK) {
      float4 a0 = make_float4(0,0,0,0), a1 = make_float4(0,0,0,0);
      float4 w0 = make_float4(0,0,0,0);
      if (av_ok) { a0 = *(const float4*)(ap + kb + ak);
                   a1 = *(const float4*)(ap + kb + ak + 4); }
      if (wv_ok) { w0 = *(const float4*)(wp + kb + wk); }
      __syncthreads();
      As[ak + 0][arow] = a0.x; As[ak + 1][arow] = a0.y;
      As[ak + 2][arow] = a0.z; As[ak + 3][arow] = a0.w;
      As[ak + 4][arow] = a1.x; As[ak + 5][arow] = a1.y;
      As[ak + 6][arow] = a1.z; As[ak + 7][arow] = a1.w;
      Ws[wk + 0][wrow] = w0.x; Ws[wk + 1][wrow] = w0.y;
      Ws[wk + 2][wrow] = w0.z; Ws[wk + 3][wrow] = w0.w;
      __syncthreads();
      #pragma unroll
      for (int k = 0; k < BK; ++k) {
        float4 av0 = *(const float4*)&As[k][ry * 8];
        float4 av1 = *(const float4*)&As[k][ry * 8 + 4];
        float4 bv  = *(const float4*)&Ws[k][cx * 4];
        float aa[8] = {av0.x, av0.y, av0.z, av0.w, av1.x, av1.y, av1.z, av1.w};
        float bb[4] = {bv.x, bv.y, bv.z, bv.w};
        #pragma unroll
        for (int i = 0; i < 8; ++i)
          #pragma unroll
          for (int j = 0; j < 4; ++j) acc[i][j] += aa[i] * bb[j];
      }
    }
  }

  const int gn = n0 + cx * 4;
  if (gn >= N) return;            // N%4==0, whole float4 valid or skipped
  float bs[4] = {0, 0, 0, 0};
  if (b1) { for (int j = 0; j < 4; ++j) bs[j] += b1[gn + j]; }
  if (PAIRS == 2 && b2) { for (int j = 0; j < 4; ++j) bs[j] += b2[gn + j]; }
  #pragma unroll
  for (int i = 0; i < 8; ++i) {
    int gm = m0 + ry * 8 + i;
    if (gm >= M) continue;
    float ov[4];
    #pragma unroll
    for (int j = 0; j < 4; ++j) {
      float xv = acc[i][j] + bs[j];
      if (ACT == 1) xv = fmaxf(xv, 0.f);
      if (ACT == 2) xv = tanhf(xv);
      ov[j] = xv;
    }
    if (HASADD) {
      float4 ad = *(const float4*)(add + (long)gm * ldc + gn);
      ov[0] += ad.x; ov[1] += ad.y; ov[2] += ad.z; ov[3] += ad.w;
    }
    *(float4*)(C + (long)gm * ldc + gn) = make_float4(ov[0], ov[1], ov[2], ov[3]);
  }
}

// ---------------------------------------------------------------------------
// f32 NN GEMM (out2 = S @ q3): A (M x K) lda, B (K x N) row-major ldb.
// 128x64 tile, BK=16, 8x4 acc. Batched via grid.z (A/B/C strides).
// B rows beyond Kvalid are treated as 0 (S pad cols are zeroed anyway).
// ---------------------------------------------------------------------------
__global__ __launch_bounds__(256)
void sgemm_nn(const float* __restrict__ Abuf, const float* __restrict__ Bbuf,
              float* __restrict__ C,
              int M, int N, int K, int Kvalid, int lda, int ldb, int ldc,
              long sA, long sB, long sC)
{
  __shared__ float As[BK][BM + 4];
  __shared__ float Bs[BK][BN + 4];
  const int bz = blockIdx.z;
  const float* A = Abuf + (long)bz * sA;
  const float* B = Bbuf + (long)bz * sB;
  float* Cb = C + (long)bz * sC;
  const int m0 = blockIdx.x * BM, n0 = blockIdx.y * BN;
  const int tid = threadIdx.x;
  const int arow = tid >> 1, ak = (tid & 1) * 8;
  const int bk = tid >> 4, bn = (tid & 15) * 4;
  const int cx = tid & 15, ry = tid >> 4;
  float acc[8][4] = {};

  const int gm = m0 + arow;
  const float* ap = A + (long)gm * lda;
  const bool av_ok = gm < M;
  for (int kb = 0; kb < K; kb += BK) {
    float4 a0 = make_float4(0,0,0,0), a1 = make_float4(0,0,0,0);
    float4 b0 = make_float4(0,0,0,0);
    if (av_ok) { a0 = *(const float4*)(ap + kb + ak);
                 a1 = *(const float4*)(ap + kb + ak + 4); }
    int w = kb + bk;
    if (w < Kvalid) b0 = *(const float4*)(B + (long)w * ldb + n0 + bn);
    __syncthreads();
    As[ak + 0][arow] = a0.x; As[ak + 1][arow] = a0.y;
    As[ak + 2][arow] = a0.z; As[ak + 3][arow] = a0.w;
    As[ak + 4][arow] = a1.x; As[ak + 5][arow] = a1.y;
    As[ak + 6][arow] = a1.z; As[ak + 7][arow] = a1.w;
    *(float4*)&Bs[bk][bn] = b0;
    __syncthreads();
    #pragma unroll
    for (int k = 0; k < BK; ++k) {
      float4 av0 = *(const float4*)&As[k][ry * 8];
      float4 av1 = *(const float4*)&As[k][ry * 8 + 4];
      float4 bv  = *(const float4*)&Bs[k][cx * 4];
      float aa[8] = {av0.x, av0.y, av0.z, av0.w, av1.x, av1.y, av1.z, av1.w};
      float bb[4] = {bv.x, bv.y, bv.z, bv.w};
      #pragma unroll
      for (int i = 0; i < 8; ++i)
        #pragma unroll
        for (int j = 0; j < 4; ++j) acc[i][j] += aa[i] * bb[j];
    }
  }

  const int gn = n0 + cx * 4;
  #pragma unroll
  for (int i = 0; i < 8; ++i) {
    int g = m0 + ry * 8 + i;
    if (g < M)
      *(float4*)(Cb + (long)g * ldc + gn) =
          make_float4(acc[i][0], acc[i][1], acc[i][2], acc[i][3]);
  }
}

// ---------------------------------------------------------------------------
// lt[b,n,d] = sum_c l[b,c,n] * W_lang[d,c] + b_lang[d].  One block per (b,n).
// ---------------------------------------------------------------------------
__global__ __launch_bounds__(256)
void lt_kernel(const float* __restrict__ l, const float* __restrict__ Wl,
               const float* __restrict__ bl, float* __restrict__ Lt)
{
  __shared__ float lc[LIN_];
  const int b = blockIdx.x / NL_, n = blockIdx.x % NL_;
  const int tid = threadIdx.x;
  const float* lb = l + (long)b * LIN_ * NL_;
  for (int c = tid; c < LIN_; c += 256) lc[c] = lb[c * NL_ + n];
  __syncthreads();
  for (int d = tid; d < DIM_; d += 256) {
    const float* w = Wl + (long)d * LIN_;
    float acc = 0.f;
    for (int c = 0; c < LIN_; c += 4) {
      float4 wf = *(const float4*)&w[c];
      acc += lc[c] * wf.x + lc[c + 1] * wf.y + lc[c + 2] * wf.z + lc[c + 3] * wf.w;
    }
    Lt[((long)b * NL_ + n) * DIM_ + d] = acc + bl[d];
  }
}

// ---------------------------------------------------------------------------
// Fused language attention over NL=20 tokens (f32).
// ---------------------------------------------------------------------------
__global__ __launch_bounds__(256)
void attn_kernel(const float* __restrict__ Q, const float* __restrict__ Lt,
                 const float* __restrict__ lmask, float* __restrict__ O,
                 int bbase)
{
  __shared__ float lt[NL_ * DIM_];   // 40 KB
  __shared__ float smask[NL_];
  const int bg = blockIdx.y, b = bbase + bg;
  const int tid = threadIdx.x;
  const float* Lb = Lt + (long)b * NL_ * DIM_;
  for (int i = tid; i < NL_ * DIM_ / 4; i += 256)
    *(float4*)&lt[i * 4] = *(const float4*)&Lb[i * 4];
  if (tid < NL_) smask[tid] = 10000.f * lmask[b * NL_ + tid] - 10000.f;
  __syncthreads();
  const int wid = tid >> 6, lane = tid & 63;
  for (int rr = 0; rr < 2; ++rr) {
    int h = blockIdx.x * 8 + wid * 2 + rr;
    if (h >= HW_) continue;  // wave-uniform
    long grow = ((long)bg * HW_ + h) * DIM_;
    float4 q0 = *(const float4*)&Q[grow + lane * 8];
    float4 q1 = *(const float4*)&Q[grow + lane * 8 + 4];
    float sim[NL_];
    for (int n = 0; n < NL_; ++n) {
      const float* lv = &lt[n * DIM_ + lane * 8];
      float4 l0 = *(const float4*)lv, l1 = *(const float4*)(lv + 4);
      float d = q0.x * l0.x + q0.y * l0.y + q0.z * l0.z + q0.w * l0.w
              + q1.x * l1.x + q1.y * l1.y + q1.z * l1.z + q1.w * l1.w;
      #pragma unroll
      for (int m = 32; m >= 1; m >>= 1) d += __shfl_xor(d, m, 64);
      sim[n] = d + smask[n];
    }
    float mx = sim[0];
    #pragma unroll
    for (int n = 1; n < NL_; ++n) mx = fmaxf(mx, sim[n]);
    float s = 0.f;
    #pragma unroll
    for (int n = 0; n < NL_; ++n) { sim[n] = expf(sim[n] - mx); s += sim[n]; }
    float inv = 1.f / s;
    float o[8] = {0, 0, 0, 0, 0, 0, 0, 0};
    for (int n = 0; n < NL_; ++n) {
      float pn = sim[n] * inv;
      const float* lv = &lt[n * DIM_ + lane * 8];
      float4 l0 = *(const float4*)lv, l1 = *(const float4*)(lv + 4);
      o[0] += pn * l0.x; o[1] += pn * l0.y; o[2] += pn * l0.z; o[3] += pn * l0.w;
      o[4] += pn * l1.x; o[5] += pn * l1.y; o[6] += pn * l1.z; o[7] += pn * l1.w;
    }
    *(float4*)&O[grow + lane * 8] = make_float4(o[0], o[1], o[2], o[3]);
    *(float4*)&O[grow + lane * 8 + 4] = make_float4(o[4], o[5], o[6], o[7]);
  }
}

// ---------------------------------------------------------------------------
// Row softmax over 900 valid cols (stride SPAD); zeroes pad cols [900,912).
// One block per row.
// ---------------------------------------------------------------------------
__global__ __launch_bounds__(256)
void softmax_rows(float* __restrict__ S)
{
  __shared__ float red[4];
  float* p = S + (long)blockIdx.x * SPAD;
  const int tid = threadIdx.x, lane = tid & 63, wid = tid >> 6;
  float vals[4];
  float mx = -1e30f;
  #pragma unroll
  for (int i = 0; i < 4; ++i) {
    int idx = tid + i * 256;
    vals[i] = (idx < HW_) ? p[idx] : -1e30f;
    mx = fmaxf(mx, vals[i]);
  }
  #pragma unroll
  for (int m = 32; m >= 1; m >>= 1) mx = fmaxf(mx, __shfl_xor(mx, m, 64));
  if (lane == 0) red[wid] = mx;
  __syncthreads();
  mx = fmaxf(fmaxf(red[0], red[1]), fmaxf(red[2], red[3]));
  __syncthreads();
  float s = 0.f;
  #pragma unroll
  for (int i = 0; i < 4; ++i) {
    int idx = tid + i * 256;
    if (idx < HW_) { vals[i] = expf(vals[i] - mx); s += vals[i]; }
  }
  #pragma unroll
  for (int m = 32; m >= 1; m >>= 1) s += __shfl_xor(s, m, 64);
  if (lane == 0) red[wid] = s;
  __syncthreads();
  float inv = 1.f / (red[0] + red[1] + red[2] + red[3]);
  #pragma unroll
  for (int i = 0; i < 4; ++i) {
    int idx = tid + i * 256;
    if (idx < HW_) p[idx] = vals[i] * inv;
  }
  if (tid < SPAD - HW_) p[HW_ + tid] = 0.f;
}

// ---------------------------------------------------------------------------
__global__ void diag_kernel(float* out, long n, float ws_mb)
{
  long i = (long)blockIdx.x * 256 + threadIdx.x;
  if (i < n) out[i] = 0.f;
  if (i == 0) out[0] = ws_mb;
}

// ---------------------------------------------------------------------------
extern "C" void kernel_launch(void* const* d_in, const int* in_sizes, int n_in,
                              void* d_out, int out_size, void* d_ws, size_t ws_size,
                              hipStream_t stream) {
  const float* x      = (const float*)d_in[0];
  const float* l      = (const float*)d_in[1];
  const float* lmask  = (const float*)d_in[2];
  const float* W_lang = (const float*)d_in[3];
  const float* b_lang = (const float*)d_in[4];
  const float* W_v1   = (const float*)d_in[5];  const float* b_v1   = (const float*)d_in[6];
  const float* W_v2   = (const float*)d_in[7];  const float* b_v2   = (const float*)d_in[8];
  const float* W_v3   = (const float*)d_in[9];  const float* b_v3   = (const float*)d_in[10];
  const float* W_v4   = (const float*)d_in[11]; const float* b_v4   = (const float*)d_in[12];
  const float* W_out1 = (const float*)d_in[13]; const float* b_out1 = (const float*)d_in[14];
  const float* W_v22  = (const float*)d_in[15]; const float* b_v22  = (const float*)d_in[16];
  const float* W_a    = (const float*)d_in[17]; const float* b_a    = (const float*)d_in[18];
  const float* W_o3   = (const float*)d_in[19]; const float* b_o3   = (const float*)d_in[20];
  float* out = (float*)d_out;

  const size_t nG  = (size_t)MG * DIM_;              // 3,686,400 f32 (group buffer)
  const size_t nS  = (size_t)MH * SPAD;              // 3,283,200 f32 (half-group S)
  const size_t nLt = (size_t)BATCH * NL_ * DIM_;     // 327,680 f32
  const size_t need = (3 * nG + nS + nLt) * sizeof(float);  // 58,680,320 B

  if (ws_size < need) {
    long n = (long)out_size;
    diag_kernel<<<dim3((unsigned)((n + 255) / 256)), dim3(256), 0, stream>>>(
        out, n, (float)(ws_size >> 20));
    return;
  }

  float* ws = (float*)d_ws;
  float* O  = ws;            // attention out (group of 8)
  float* Ap = O + nG;        // Apre -> out2 in place (group of 8)
  float* Q3 = Ap + nG;       // q3 (group of 8)
  float* S  = Q3 + nG;       // scores (half-group of 4, stride SPAD)
  float* Lt = S + nS;        // (B, 20, 512), all batches

  dim3 blk(256);
  dim3 gg((MG + BM - 1) / BM, DIM_ / BN);           // (57, 8) regular TN gemms
  dim3 gs((MH + BM - 1) / BM, (HW_ + BN - 1) / BN); // (29, 15) S gemm
  dim3 go((HW_ + BM - 1) / BM, DIM_ / BN, HB);      // (8, 8, 4) out2 NN gemm

  // 1. lt (all batches)
  lt_kernel<<<dim3(BATCH * NL_), blk, 0, stream>>>(l, W_lang, b_lang, Lt);

  for (int g = 0; g < NGRP; ++g) {
    const float* xg = x + (size_t)g * nG;
    float* outg = out + (size_t)g * nG;
    // 2. q1 = relu(x W_v1^T + b) -> d_out group rows
    sgemm_tn<1,1,0><<<gg, blk, 0, stream>>>(
        xg, W_v1, nullptr, nullptr, b_v1, nullptr, nullptr, outg,
        MG, DIM_, DIM_, DIM_, DIM_, 0, 0, 0, DIM_);
    // 3. attention -> O
    attn_kernel<<<dim3(113, G_), blk, 0, stream>>>(outg, Lt, lmask, O, g * G_);
    // 4. q2 -> d_out
    sgemm_tn<1,1,0><<<gg, blk, 0, stream>>>(
        xg, W_v2, nullptr, nullptr, b_v2, nullptr, nullptr, outg,
        MG, DIM_, DIM_, DIM_, DIM_, 0, 0, 0, DIM_);
    // 5. Apre = tanh(O W_out1^T + q2 W_v22^T + b+b) -> Ap
    sgemm_tn<2,2,0><<<gg, blk, 0, stream>>>(
        O, W_out1, outg, W_v22, b_out1, b_v22, nullptr, Ap,
        MG, DIM_, DIM_, DIM_, DIM_, DIM_, DIM_, DIM_, DIM_);
    // 6. q3 = relu(x W_v3^T + b) -> Q3
    sgemm_tn<1,1,0><<<gg, blk, 0, stream>>>(
        xg, W_v3, nullptr, nullptr, b_v3, nullptr, nullptr, Q3,
        MG, DIM_, DIM_, DIM_, DIM_, 0, 0, 0, DIM_);
    // 7. per half-group: S-gemm, softmax, out2 (out2 overwrites Ap half)
    for (int h = 0; h < 2; ++h) {
      float* Aph = Ap + (size_t)h * MH * DIM_;
      float* Q3h = Q3 + (size_t)h * MH * DIM_;
      // 7a. S = Aph @ W_a^T + b_a  (M=3600, N=900, ldc=SPAD)
      sgemm_tn<0,1,0><<<gs, blk, 0, stream>>>(
          Aph, W_a, nullptr, nullptr, b_a, nullptr, nullptr, S,
          MH, HW_, DIM_, DIM_, DIM_, 0, 0, 0, SPAD);
      // 7b. row softmax (+ zero pad cols)
      softmax_rows<<<dim3(MH), blk, 0, stream>>>(S);
      // 7c. out2 = S @ q3  (batched per batch-in-half; overwrites Aph)
      sgemm_nn<<<go, blk, 0, stream>>>(
          S, Q3h, Aph, HW_, DIM_, SPAD, HW_, SPAD, DIM_, DIM_,
          (long)HW_ * SPAD, (long)HW_ * DIM_, (long)HW_ * DIM_);
    }
    // 8. q4 -> d_out
    sgemm_tn<1,1,0><<<gg, blk, 0, stream>>>(
        xg, W_v4, nullptr, nullptr, b_v4, nullptr, nullptr, outg,
        MG, DIM_, DIM_, DIM_, DIM_, 0, 0, 0, DIM_);
    // 9. out = relu(out2 Wo3[:,:512]^T + O Wo3[:,512:]^T + b_o3) + q4
    //    addend (q4) aliases C: same-element read-before-write, safe.
    sgemm_tn<1,2,1><<<gg, blk, 0, stream>>>(
        Ap, W_o3, O, W_o3 + DIM_, b_o3, nullptr, outg, outg,
        MG, DIM_, DIM_, DIM_, DIM_ * 2, DIM_, DIM_, DIM_ * 2, DIM_);
  }
}

// Round 6
// 3311.780 us; speedup vs baseline: 2.1850x; 1.0649x over previous
//
#include <hip/hip_runtime.h>

#define BATCH 32
#define HW_ 900
#define NL_ 20
#define DIM_ 512
#define LIN_ 768
#define SPAD 912        // S row stride (zero-padded cols 900..911)

#define BM 128
#define BN 64
#define BK 32

// ---------------------------------------------------------------------------
// f32 TN GEMM: C = act( A1*W1^T [+ A2*W2^T] + b1 [+ b2] )
// A (M x K) lda, W (N x K) row-major ldw. 128x64 tile, BK=32, 256 threads,
// 8x4 acc per thread, register prefetch of next K-tile.
// Requires K % 32 == 0, N % 4 == 0.
// ---------------------------------------------------------------------------
template<int ACT, int PAIRS>
__global__ __launch_bounds__(256)
void sgemm_tn(const float* __restrict__ A1, const float* __restrict__ W1,
              const float* __restrict__ A2, const float* __restrict__ W2,
              const float* __restrict__ b1, const float* __restrict__ b2,
              float* __restrict__ C,
              int M, int N, int K1, int lda, int ldw,
              int K2, int lda2, int ldw2, int ldc)
{
  __shared__ float As[BK][BM + 4];   // 16896 B
  __shared__ float Ws[BK][BN + 4];   // 8704 B
  const int m0 = blockIdx.x * BM, n0 = blockIdx.y * BN;
  const int tid = threadIdx.x;
  const int arow = tid >> 1, ak = (tid & 1) * 16;   // A: 128 rows x 32k, 16 f/thread
  const int wrow = tid & 63, wk = (tid >> 6) * 8;   // W: 64 rows x 32k, 8 f/thread
  const int cx = tid & 15, ry = tid >> 4;
  float acc[8][4] = {};

  for (int p = 0; p < PAIRS; ++p) {
    const float* A = p ? A2 : A1;
    const float* W = p ? W2 : W1;
    const int la = p ? lda2 : lda, lw = p ? ldw2 : ldw, K = p ? K2 : K1;
    const int gm = m0 + arow, gn = n0 + wrow;
    const float* ap = A + (long)gm * la + ak;
    const float* wp = W + (long)gn * lw + wk;
    const bool aok = gm < M, wok = gn < N;
    float4 a[4], w[2];
    #pragma unroll
    for (int j = 0; j < 4; ++j)
      a[j] = aok ? *(const float4*)(ap + j * 4) : make_float4(0, 0, 0, 0);
    #pragma unroll
    for (int j = 0; j < 2; ++j)
      w[j] = wok ? *(const float4*)(wp + j * 4) : make_float4(0, 0, 0, 0);
    for (int kb = 0; kb < K; kb += BK) {
      __syncthreads();
      #pragma unroll
      for (int j = 0; j < 4; ++j) {
        As[ak + j * 4 + 0][arow] = a[j].x; As[ak + j * 4 + 1][arow] = a[j].y;
        As[ak + j * 4 + 2][arow] = a[j].z; As[ak + j * 4 + 3][arow] = a[j].w;
      }
      #pragma unroll
      for (int j = 0; j < 2; ++j) {
        Ws[wk + j * 4 + 0][wrow] = w[j].x; Ws[wk + j * 4 + 1][wrow] = w[j].y;
        Ws[wk + j * 4 + 2][wrow] = w[j].z; Ws[wk + j * 4 + 3][wrow] = w[j].w;
      }
      __syncthreads();
      if (kb + BK < K) {   // prefetch next tile into regs (overlaps compute)
        #pragma unroll
        for (int j = 0; j < 4; ++j)
          a[j] = aok ? *(const float4*)(ap + kb + BK + j * 4) : make_float4(0,0,0,0);
        #pragma unroll
        for (int j = 0; j < 2; ++j)
          w[j] = wok ? *(const float4*)(wp + kb + BK + j * 4) : make_float4(0,0,0,0);
      }
      #pragma unroll
      for (int k = 0; k < BK; ++k) {
        float4 av0 = *(const float4*)&As[k][ry * 8];
        float4 av1 = *(const float4*)&As[k][ry * 8 + 4];
        float4 bv  = *(const float4*)&Ws[k][cx * 4];
        float aa[8] = {av0.x, av0.y, av0.z, av0.w, av1.x, av1.y, av1.z, av1.w};
        float bb[4] = {bv.x, bv.y, bv.z, bv.w};
        #pragma unroll
        for (int i = 0; i < 8; ++i)
          #pragma unroll
          for (int j = 0; j < 4; ++j) acc[i][j] += aa[i] * bb[j];
      }
    }
  }

  const int gn = n0 + cx * 4;
  if (gn >= N) return;
  float bs[4] = {0, 0, 0, 0};
  if (b1) { for (int j = 0; j < 4; ++j) bs[j] += b1[gn + j]; }
  if (PAIRS == 2 && b2) { for (int j = 0; j < 4; ++j) bs[j] += b2[gn + j]; }
  #pragma unroll
  for (int i = 0; i < 8; ++i) {
    int gm = m0 + ry * 8 + i;
    if (gm >= M) continue;
    float ov[4];
    #pragma unroll
    for (int j = 0; j < 4; ++j) {
      float xv = acc[i][j] + bs[j];
      if (ACT == 1) xv = fmaxf(xv, 0.f);
      if (ACT == 2) xv = tanhf(xv);
      ov[j] = xv;
    }
    *(float4*)(C + (long)gm * ldc + gn) = make_float4(ov[0], ov[1], ov[2], ov[3]);
  }
}

// ---------------------------------------------------------------------------
// Final fused GEMM: C = relu(A1*W1^T + A2*W2^T + b1) + relu(A3*W3^T + b3)
// (out = relu(out2·Wo3a + O·Wo3b + b_o3) + relu(x·Wv4 + b_v4)). K=512 all.
// ---------------------------------------------------------------------------
__global__ __launch_bounds__(256)
void sgemm_final(const float* __restrict__ A1, const float* __restrict__ W1,
                 const float* __restrict__ A2, const float* __restrict__ W2,
                 const float* __restrict__ A3, const float* __restrict__ W3,
                 const float* __restrict__ b1, const float* __restrict__ b3,
                 float* __restrict__ C,
                 int M, int N, int lda, int ldw12, int ldw3, int ldc)
{
  __shared__ float As[BK][BM + 4];
  __shared__ float Ws[BK][BN + 4];
  const int m0 = blockIdx.x * BM, n0 = blockIdx.y * BN;
  const int tid = threadIdx.x;
  const int arow = tid >> 1, ak = (tid & 1) * 16;
  const int wrow = tid & 63, wk = (tid >> 6) * 8;
  const int cx = tid & 15, ry = tid >> 4;
  float accM[8][4] = {};
  float accQ[8][4] = {};

  for (int p = 0; p < 3; ++p) {
    const float* A = (p == 0) ? A1 : (p == 1) ? A2 : A3;
    const float* W = (p == 0) ? W1 : (p == 1) ? W2 : W3;
    const int lw = (p == 2) ? ldw3 : ldw12;
    const int gm = m0 + arow, gn = n0 + wrow;
    const float* ap = A + (long)gm * lda + ak;
    const float* wp = W + (long)gn * lw + wk;
    const bool aok = gm < M, wok = gn < N;
    float4 a[4], w[2];
    #pragma unroll
    for (int j = 0; j < 4; ++j)
      a[j] = aok ? *(const float4*)(ap + j * 4) : make_float4(0, 0, 0, 0);
    #pragma unroll
    for (int j = 0; j < 2; ++j)
      w[j] = wok ? *(const float4*)(wp + j * 4) : make_float4(0, 0, 0, 0);
    for (int kb = 0; kb < DIM_; kb += BK) {
      __syncthreads();
      #pragma unroll
      for (int j = 0; j < 4; ++j) {
        As[ak + j * 4 + 0][arow] = a[j].x; As[ak + j * 4 + 1][arow] = a[j].y;
        As[ak + j * 4 + 2][arow] = a[j].z; As[ak + j * 4 + 3][arow] = a[j].w;
      }
      #pragma unroll
      for (int j = 0; j < 2; ++j) {
        Ws[wk + j * 4 + 0][wrow] = w[j].x; Ws[wk + j * 4 + 1][wrow] = w[j].y;
        Ws[wk + j * 4 + 2][wrow] = w[j].z; Ws[wk + j * 4 + 3][wrow] = w[j].w;
      }
      __syncthreads();
      if (kb + BK < DIM_) {
        #pragma unroll
        for (int j = 0; j < 4; ++j)
          a[j] = aok ? *(const float4*)(ap + kb + BK + j * 4) : make_float4(0,0,0,0);
        #pragma unroll
        for (int j = 0; j < 2; ++j)
          w[j] = wok ? *(const float4*)(wp + kb + BK + j * 4) : make_float4(0,0,0,0);
      }
      #pragma unroll
      for (int k = 0; k < BK; ++k) {
        float4 av0 = *(const float4*)&As[k][ry * 8];
        float4 av1 = *(const float4*)&As[k][ry * 8 + 4];
        float4 bv  = *(const float4*)&Ws[k][cx * 4];
        float aa[8] = {av0.x, av0.y, av0.z, av0.w, av1.x, av1.y, av1.z, av1.w};
        float bb[4] = {bv.x, bv.y, bv.z, bv.w};
        if (p < 2) {
          #pragma unroll
          for (int i = 0; i < 8; ++i)
            #pragma unroll
            for (int j = 0; j < 4; ++j) accM[i][j] += aa[i] * bb[j];
        } else {
          #pragma unroll
          for (int i = 0; i < 8; ++i)
            #pragma unroll
            for (int j = 0; j < 4; ++j) accQ[i][j] += aa[i] * bb[j];
        }
      }
    }
  }

  const int gn = n0 + cx * 4;
  if (gn >= N) return;
  float bsM[4], bsQ[4];
  #pragma unroll
  for (int j = 0; j < 4; ++j) { bsM[j] = b1[gn + j]; bsQ[j] = b3[gn + j]; }
  #pragma unroll
  for (int i = 0; i < 8; ++i) {
    int gm = m0 + ry * 8 + i;
    if (gm >= M) continue;
    float ov[4];
    #pragma unroll
    for (int j = 0; j < 4; ++j)
      ov[j] = fmaxf(accM[i][j] + bsM[j], 0.f) + fmaxf(accQ[i][j] + bsQ[j], 0.f);
    *(float4*)(C + (long)gm * ldc + gn) = make_float4(ov[0], ov[1], ov[2], ov[3]);
  }
}

// ---------------------------------------------------------------------------
// f32 NN GEMM (out2 = S @ q3), batched via grid.z. (round-5, verified)
// ---------------------------------------------------------------------------
#define NBK 16
__global__ __launch_bounds__(256)
void sgemm_nn(const float* __restrict__ Abuf, const float* __restrict__ Bbuf,
              float* __restrict__ C,
              int M, int N, int K, int Kvalid, int lda, int ldb, int ldc,
              long sA, long sB, long sC)
{
  __shared__ float As[NBK][BM + 4];
  __shared__ float Bs[NBK][BN + 4];
  const int bz = blockIdx.z;
  const float* A = Abuf + (long)bz * sA;
  const float* B = Bbuf + (long)bz * sB;
  float* Cb = C + (long)bz * sC;
  const int m0 = blockIdx.x * BM, n0 = blockIdx.y * BN;
  const int tid = threadIdx.x;
  const int arow = tid >> 1, ak = (tid & 1) * 8;
  const int bk = tid >> 4, bn = (tid & 15) * 4;
  const int cx = tid & 15, ry = tid >> 4;
  float acc[8][4] = {};

  const int gm = m0 + arow;
  const float* ap = A + (long)gm * lda;
  const bool av_ok = gm < M;
  for (int kb = 0; kb < K; kb += NBK) {
    float4 a0 = make_float4(0,0,0,0), a1 = make_float4(0,0,0,0);
    float4 b0 = make_float4(0,0,0,0);
    if (av_ok) { a0 = *(const float4*)(ap + kb + ak);
                 a1 = *(const float4*)(ap + kb + ak + 4); }
    int w = kb + bk;
    if (w < Kvalid) b0 = *(const float4*)(B + (long)w * ldb + n0 + bn);
    __syncthreads();
    As[ak + 0][arow] = a0.x; As[ak + 1][arow] = a0.y;
    As[ak + 2][arow] = a0.z; As[ak + 3][arow] = a0.w;
    As[ak + 4][arow] = a1.x; As[ak + 5][arow] = a1.y;
    As[ak + 6][arow] = a1.z; As[ak + 7][arow] = a1.w;
    *(float4*)&Bs[bk][bn] = b0;
    __syncthreads();
    #pragma unroll
    for (int k = 0; k < NBK; ++k) {
      float4 av0 = *(const float4*)&As[k][ry * 8];
      float4 av1 = *(const float4*)&As[k][ry * 8 + 4];
      float4 bv  = *(const float4*)&Bs[k][cx * 4];
      float aa[8] = {av0.x, av0.y, av0.z, av0.w, av1.x, av1.y, av1.z, av1.w};
      float bb[4] = {bv.x, bv.y, bv.z, bv.w};
      #pragma unroll
      for (int i = 0; i < 8; ++i)
        #pragma unroll
        for (int j = 0; j < 4; ++j) acc[i][j] += aa[i] * bb[j];
    }
  }
  const int gn = n0 + cx * 4;
  #pragma unroll
  for (int i = 0; i < 8; ++i) {
    int g = m0 + ry * 8 + i;
    if (g < M)
      *(float4*)(Cb + (long)g * ldc + gn) =
          make_float4(acc[i][0], acc[i][1], acc[i][2], acc[i][3]);
  }
}

// ---------------------------------------------------------------------------
// Transpose l: Ltr[b][n][c] = l[b][c][n].  One block per b, coalesced reads.
// ---------------------------------------------------------------------------
__global__ __launch_bounds__(256)
void transpose_l(const float* __restrict__ l, float* __restrict__ Ltr)
{
  const int b = blockIdx.x;
  const float* lb = l + (long)b * LIN_ * NL_;
  float* ob = Ltr + (long)b * NL_ * LIN_;
  for (int i = threadIdx.x; i < LIN_ * NL_; i += 256) {
    int c = i / NL_, n = i % NL_;
    ob[(long)n * LIN_ + c] = lb[i];
  }
}

// ---------------------------------------------------------------------------
// Fused language attention over NL=20 tokens (f32).  (round-5, verified)
// ---------------------------------------------------------------------------
__global__ __launch_bounds__(256)
void attn_kernel(const float* __restrict__ Q, const float* __restrict__ Lt,
                 const float* __restrict__ lmask, float* __restrict__ O,
                 int bbase)
{
  __shared__ float lt[NL_ * DIM_];
  __shared__ float smask[NL_];
  const int bg = blockIdx.y, b = bbase + bg;
  const int tid = threadIdx.x;
  const float* Lb = Lt + (long)b * NL_ * DIM_;
  for (int i = tid; i < NL_ * DIM_ / 4; i += 256)
    *(float4*)&lt[i * 4] = *(const float4*)&Lb[i * 4];
  if (tid < NL_) smask[tid] = 10000.f * lmask[b * NL_ + tid] - 10000.f;
  __syncthreads();
  const int wid = tid >> 6, lane = tid & 63;
  for (int rr = 0; rr < 2; ++rr) {
    int h = blockIdx.x * 8 + wid * 2 + rr;
    if (h >= HW_) continue;
    long grow = ((long)bg * HW_ + h) * DIM_;
    float4 q0 = *(const float4*)&Q[grow + lane * 8];
    float4 q1 = *(const float4*)&Q[grow + lane * 8 + 4];
    float sim[NL_];
    for (int n = 0; n < NL_; ++n) {
      const float* lv = &lt[n * DIM_ + lane * 8];
      float4 l0 = *(const float4*)lv, l1 = *(const float4*)(lv + 4);
      float d = q0.x * l0.x + q0.y * l0.y + q0.z * l0.z + q0.w * l0.w
              + q1.x * l1.x + q1.y * l1.y + q1.z * l1.z + q1.w * l1.w;
      #pragma unroll
      for (int m = 32; m >= 1; m >>= 1) d += __shfl_xor(d, m, 64);
      sim[n] = d + smask[n];
    }
    float mx = sim[0];
    #pragma unroll
    for (int n = 1; n < NL_; ++n) mx = fmaxf(mx, sim[n]);
    float s = 0.f;
    #pragma unroll
    for (int n = 0; n < NL_; ++n) { sim[n] = expf(sim[n] - mx); s += sim[n]; }
    float inv = 1.f / s;
    float o[8] = {0, 0, 0, 0, 0, 0, 0, 0};
    for (int n = 0; n < NL_; ++n) {
      float pn = sim[n] * inv;
      const float* lv = &lt[n * DIM_ + lane * 8];
      float4 l0 = *(const float4*)lv, l1 = *(const float4*)(lv + 4);
      o[0] += pn * l0.x; o[1] += pn * l0.y; o[2] += pn * l0.z; o[3] += pn * l0.w;
      o[4] += pn * l1.x; o[5] += pn * l1.y; o[6] += pn * l1.z; o[7] += pn * l1.w;
    }
    *(float4*)&O[grow + lane * 8] = make_float4(o[0], o[1], o[2], o[3]);
    *(float4*)&O[grow + lane * 8 + 4] = make_float4(o[4], o[5], o[6], o[7]);
  }
}

// ---------------------------------------------------------------------------
// Row softmax over 900 cols (stride SPAD); zeroes pad cols. One block/row.
// ---------------------------------------------------------------------------
__global__ __launch_bounds__(256)
void softmax_rows(float* __restrict__ S)
{
  __shared__ float red[4];
  float* p = S + (long)blockIdx.x * SPAD;
  const int tid = threadIdx.x, lane = tid & 63, wid = tid >> 6;
  float vals[4];
  float mx = -1e30f;
  #pragma unroll
  for (int i = 0; i < 4; ++i) {
    int idx = tid + i * 256;
    vals[i] = (idx < HW_) ? p[idx] : -1e30f;
    mx = fmaxf(mx, vals[i]);
  }
  #pragma unroll
  for (int m = 32; m >= 1; m >>= 1) mx = fmaxf(mx, __shfl_xor(mx, m, 64));
  if (lane == 0) red[wid] = mx;
  __syncthreads();
  mx = fmaxf(fmaxf(red[0], red[1]), fmaxf(red[2], red[3]));
  __syncthreads();
  float s = 0.f;
  #pragma unroll
  for (int i = 0; i < 4; ++i) {
    int idx = tid + i * 256;
    if (idx < HW_) { vals[i] = expf(vals[i] - mx); s += vals[i]; }
  }
  #pragma unroll
  for (int m = 32; m >= 1; m >>= 1) s += __shfl_xor(s, m, 64);
  if (lane == 0) red[wid] = s;
  __syncthreads();
  float inv = 1.f / (red[0] + red[1] + red[2] + red[3]);
  #pragma unroll
  for (int i = 0; i < 4; ++i) {
    int idx = tid + i * 256;
    if (idx < HW_) p[idx] = vals[i] * inv;
  }
  if (tid < SPAD - HW_) p[HW_ + tid] = 0.f;
}

// ---------------------------------------------------------------------------
__global__ void diag_kernel(float* out, long n, float ws_mb)
{
  long i = (long)blockIdx.x * 256 + threadIdx.x;
  if (i < n) out[i] = 0.f;
  if (i == 0) out[0] = ws_mb;
}

// ---------------------------------------------------------------------------
static size_t ws_need(int NB) {
  return (2 * (size_t)NB * HW_ * DIM_              // O + Ap
          + (size_t)(NB / 2) * HW_ * SPAD          // S (half-chunk)
          + (size_t)BATCH * NL_ * DIM_             // Lt
          + (size_t)BATCH * NL_ * LIN_) * 4;       // Ltr
}

extern "C" void kernel_launch(void* const* d_in, const int* in_sizes, int n_in,
                              void* d_out, int out_size, void* d_ws, size_t ws_size,
                              hipStream_t stream) {
  const float* x      = (const float*)d_in[0];
  const float* l      = (const float*)d_in[1];
  const float* lmask  = (const float*)d_in[2];
  const float* W_lang = (const float*)d_in[3];
  const float* b_lang = (const float*)d_in[4];
  const float* W_v1   = (const float*)d_in[5];  const float* b_v1   = (const float*)d_in[6];
  const float* W_v2   = (const float*)d_in[7];  const float* b_v2   = (const float*)d_in[8];
  const float* W_v3   = (const float*)d_in[9];  const float* b_v3   = (const float*)d_in[10];
  const float* W_v4   = (const float*)d_in[11]; const float* b_v4   = (const float*)d_in[12];
  const float* W_out1 = (const float*)d_in[13]; const float* b_out1 = (const float*)d_in[14];
  const float* W_v22  = (const float*)d_in[15]; const float* b_v22  = (const float*)d_in[16];
  const float* W_a    = (const float*)d_in[17]; const float* b_a    = (const float*)d_in[18];
  const float* W_o3   = (const float*)d_in[19]; const float* b_o3   = (const float*)d_in[20];
  float* out = (float*)d_out;

  // Tier selection by workspace size (constant per process -> graph-safe).
  int NB;
  if      (ws_size >= ws_need(32)) NB = 32;   // 173.9 MB
  else if (ws_size >= ws_need(16)) NB = 16;   //  88.8 MB
  else if (ws_size >= ws_need(8))  NB = 8;    //  46.3 MB (proven safe)
  else {
    long n = (long)out_size;
    diag_kernel<<<dim3((unsigned)((n + 255) / 256)), dim3(256), 0, stream>>>(
        out, n, (float)(ws_size >> 20));
    return;
  }

  const int nChunk = BATCH / NB;
  const int MC = NB * HW_;            // rows per chunk
  const int MHc = (NB / 2) * HW_;     // rows per S half-chunk
  const size_t nC = (size_t)MC * DIM_;          // floats per chunk buffer
  const size_t nS = (size_t)MHc * SPAD;

  float* ws = (float*)d_ws;
  float* O   = ws;
  float* Ap  = O + nC;
  float* S   = Ap + nC;
  float* Lt  = S + nS;
  float* Ltr = Lt + (size_t)BATCH * NL_ * DIM_;

  dim3 blk(256);
  dim3 gq((MC + BM - 1) / BM, DIM_ / BN);
  dim3 gs((MHc + BM - 1) / BM, (HW_ + BN - 1) / BN);
  dim3 go((HW_ + BM - 1) / BM, DIM_ / BN, NB / 2);

  // lt = l^T @ W_lang^T + b_lang  (transpose, then GEMM: M=640, K=768, N=512)
  transpose_l<<<dim3(BATCH), blk, 0, stream>>>(l, Ltr);
  sgemm_tn<0,1><<<dim3((BATCH * NL_ + BM - 1) / BM, DIM_ / BN), blk, 0, stream>>>(
      Ltr, W_lang, nullptr, nullptr, b_lang, nullptr, Lt,
      BATCH * NL_, DIM_, LIN_, LIN_, LIN_, 0, 0, 0, DIM_);

  for (int g = 0; g < nChunk; ++g) {
    const float* xg = x + (size_t)g * nC;
    float* outg = out + (size_t)g * nC;
    // q1 = relu(x W_v1^T + b) -> d_out chunk rows
    sgemm_tn<1,1><<<gq, blk, 0, stream>>>(
        xg, W_v1, nullptr, nullptr, b_v1, nullptr, outg,
        MC, DIM_, DIM_, DIM_, DIM_, 0, 0, 0, DIM_);
    // attention -> O
    attn_kernel<<<dim3(113, NB), blk, 0, stream>>>(outg, Lt, lmask, O, g * NB);
    // q2 -> d_out
    sgemm_tn<1,1><<<gq, blk, 0, stream>>>(
        xg, W_v2, nullptr, nullptr, b_v2, nullptr, outg,
        MC, DIM_, DIM_, DIM_, DIM_, 0, 0, 0, DIM_);
    // Apre = tanh(O W_out1^T + q2 W_v22^T + b + b) -> Ap
    sgemm_tn<2,2><<<gq, blk, 0, stream>>>(
        O, W_out1, outg, W_v22, b_out1, b_v22, Ap,
        MC, DIM_, DIM_, DIM_, DIM_, DIM_, DIM_, DIM_, DIM_);
    // q3 = relu(x W_v3^T + b) -> d_out
    sgemm_tn<1,1><<<gq, blk, 0, stream>>>(
        xg, W_v3, nullptr, nullptr, b_v3, nullptr, outg,
        MC, DIM_, DIM_, DIM_, DIM_, 0, 0, 0, DIM_);
    // rel_map + out2 per half-chunk (out2 overwrites Ap rows in place)
    for (int h = 0; h < 2; ++h) {
      float* Aph = Ap + (size_t)h * MHc * DIM_;
      const float* Q3h = outg + (size_t)h * MHc * DIM_;
      sgemm_tn<0,1><<<gs, blk, 0, stream>>>(
          Aph, W_a, nullptr, nullptr, b_a, nullptr, S,
          MHc, HW_, DIM_, DIM_, DIM_, 0, 0, 0, SPAD);
      softmax_rows<<<dim3(MHc), blk, 0, stream>>>(S);
      sgemm_nn<<<go, blk, 0, stream>>>(
          S, Q3h, Aph, HW_, DIM_, SPAD, HW_, SPAD, DIM_, DIM_,
          (long)HW_ * SPAD, (long)HW_ * DIM_, (long)HW_ * DIM_);
    }
    // out = relu(out2 Wo3a + O Wo3b + b_o3) + relu(x Wv4 + b_v4) -> d_out
    sgemm_final<<<gq, blk, 0, stream>>>(
        Ap, W_o3, O, W_o3 + DIM_, xg, W_v4, b_o3, b_v4, outg,
        MC, DIM_, DIM_, 2 * DIM_, DIM_, DIM_);
  }
}